// Round 4
// baseline (105.262 us; speedup 1.0000x reference)
//
#include <hip/hip_runtime.h>
#include <math.h>

#define NB 16
#define NA 5
#define NH 96
#define NW 96
#define TT 50
#define HW (NH*NW)        // 9216
#define APB (NA*HW)       // 46080 cells per batch
#define CPT 2             // cells per thread in loss_kernel (ILP vs occupancy balance)

__device__ __constant__ float c_aw[NA] = {1.3221f, 3.19275f, 5.05587f, 9.47112f, 11.2364f};
__device__ __constant__ float c_ah[NA] = {1.73145f, 4.00944f, 8.09892f, 4.84053f, 10.0071f};

__device__ __forceinline__ float sigmoidf(float x) { return 1.0f / (1.0f + __expf(-x)); }

// GT record: 8 floats per (b,t): [gxl, gxr, gyl, gyr, g06n(=-0.6*garea or -1e30), pad,pad,pad]
// prep computes the FULL assigned-cell loss for each winner and pre-subtracts the
// noobj term loss_kernel will add for that cell, so loss_kernel is branch-free per cell.
__global__ void prep_kernel(const float* __restrict__ target,
                            const float* __restrict__ outp,
                            float* __restrict__ gt,
                            float* __restrict__ out) {
    int b = blockIdx.x;
    int t = threadIdx.x;            // blockDim.x = 64 (one wave)
    __shared__ float s_gxl[TT], s_gxr[TT], s_gyl[TT], s_gyr[TT], s_g06n[TT];
    __shared__ int   s_cell[TT], s_valid[TT];

    float xraw = (t < TT) ? target[(b*TT + t)*6 + 1] : 1.0f;
    unsigned long long m = __ballot(xraw != 0.0f);

    int valid = 0, best = 0, cell = -1, gi = 0, gj = 0;
    float gx=0, gy=0, gw=1, gh=1, tcls=0, lr=0;
    float gxl=0, gxr=0, gyl=0, gyr=0, g06n=-1e30f;
    if (t < TT) {
        valid = (((~m) & ((2ull << t) - 1ull)) == 0ull) ? 1 : 0;
        const float* tg = target + (b*TT + t)*6;
        tcls = tg[0];
        gx = tg[1]*NW; gy = tg[2]*NH; gw = tg[3]*NW; gh = tg[4]*NH;
        lr = tg[5];
        float bestiou = -1.0f;
        for (int a = 0; a < NA; ++a) {
            float inter = fminf(gw, c_aw[a]) * fminf(gh, c_ah[a]);
            float iou = inter / (gw*gh + c_aw[a]*c_ah[a] - inter);
            if (iou > bestiou) { bestiou = iou; best = a; }
        }
        gi = (int)gx; gj = (int)gy;
        cell = best*HW + gj*NW + gi;
        if (valid) {
            gxl = gx - 0.5f*gw; gxr = gx + 0.5f*gw;
            gyl = gy - 0.5f*gh; gyr = gy + 0.5f*gh;
            g06n = -0.6f*gw*gh;
        }
        s_gxl[t] = gxl; s_gxr[t] = gxr; s_gyl[t] = gyl; s_gyr[t] = gyr;
        s_g06n[t] = g06n;
        s_cell[t] = valid ? cell : -1;
        s_valid[t] = valid;
        float* r = gt + (b*TT + t)*8;
        r[0] = gxl; r[1] = gxr; r[2] = gyl; r[3] = gyr; r[4] = g06n;
        r[5] = 0.0f; r[6] = 0.0f; r[7] = 0.0f;
    }
    __syncthreads();

    float acc = 0.0f;
    if (t < TT && valid) {
        int winner = 1;   // last valid t mapping to this cell wins (scan = last-write-wins)
        for (int u = t + 1; u < TT; ++u)
            if (s_valid[u] && s_cell[u] == cell) { winner = 0; break; }
        if (winner) {
            int a = cell / HW;
            int rem = cell - a*HW;
            const float* base = outp + (size_t)((b*NA + a)*8)*HW + rem;
            float o0 = base[0*HW], o1 = base[1*HW], o2 = base[2*HW], o3 = base[3*HW];
            float o4 = base[4*HW], o5 = base[5*HW], o6 = base[6*HW], o7 = base[7*HW];
            float sx = sigmoidf(o0), sy = sigmoidf(o1);
            float px = sx + (float)gi, py = sy + (float)gj;
            float pw = __expf(o2) * c_aw[a];
            float ph = __expf(o3) * c_ah[a];
            float pxl = px - 0.5f*pw, pxr = px + 0.5f*pw;
            float pyl = py - 0.5f*ph, pyr = py + 0.5f*ph;
            float parea = pw*ph, p6 = 0.6f*parea;
            // replicate loss_kernel's noobj computation exactly
            float maxv = -1e30f;
            for (int u = 0; u < TT; ++u) {
                float cw = fminf(pxr, s_gxr[u]) - fmaxf(pxl, s_gxl[u]);
                float ch = fminf(pyr, s_gyr[u]) - fmaxf(pyl, s_gyl[u]);
                float carea = fmaxf(cw, 0.0f) * fmaxf(ch, 0.0f);
                maxv = fmaxf(maxv, fmaf(1.6f, carea, s_g06n[u]));
            }
            float conf = sigmoidf(o4);
            float noobj = (maxv > p6) ? 0.0f : 0.5f*conf*conf;
            // assigned-cell loss
            float cw = fminf(pxr, gxr) - fmaxf(pxl, gxl);
            float ch = fminf(pyr, gyr) - fmaxf(pyl, gyl);
            float carea = fmaxf(cw, 0.0f) * fmaxf(ch, 0.0f);
            float tconf = carea / (parea + gw*gh - carea);
            float dc = conf - tconf;
            acc = 2.5f*dc*dc;                         // 0.5 * OBJECT_SCALE
            float tx = gx - (float)gi, ty = gy - (float)gj;
            float tw = logf(gw / c_aw[best]), th = logf(gh / c_ah[best]);
            float dx = sx - tx, dy = sy - ty, dw = o2 - tw, dh = o3 - th;
            acc += 0.5f*(dx*dx + dy*dy + dw*dw + dh*dh);
            float mm  = fmaxf(o5, o6);
            float lse = mm + __logf(__expf(o5 - mm) + __expf(o6 - mm));
            acc += lse - ((tcls != 0.0f) ? o6 : o5);  // 2-class CE
            float dl = sigmoidf(o7) - lr;
            acc += 0.25f*dl*dl;                       // 0.5 * mse_half(conf_lr)
            acc -= noobj;                             // loss_kernel will add it back
        }
    }
    // one wave -> shuffle reduce, single atomic per block
    for (int off = 32; off > 0; off >>= 1) acc += __shfl_down(acc, off, 64);
    if (t == 0) atomicAdd(out, acc * (1.0f/NB));
}

__global__ __launch_bounds__(256)
void loss_kernel(const float* __restrict__ outp,
                 const float* __restrict__ gt,
                 float* __restrict__ loss) {
    int b   = blockIdx.y;
    int tid = threadIdx.x;
    int q     = blockIdx.x*256 + tid;      // 0 .. APB/CPT-1
    int cell0 = q*CPT;
    int a   = cell0 / HW;                  // block-uniform: 9216 % 512 == 0
    int rem = cell0 - a*HW;
    int j   = rem / NW;
    int i0  = rem - j*NW;

    const float* base = outp + (size_t)((b*NA + a)*8)*HW + rem;
    float2 v0 = *(const float2*)(base + 0*HW);
    float2 v1 = *(const float2*)(base + 1*HW);
    float2 v2 = *(const float2*)(base + 2*HW);
    float2 v3 = *(const float2*)(base + 3*HW);
    float2 v4 = *(const float2*)(base + 4*HW);
    float o0[CPT] = {v0.x, v0.y};
    float o1[CPT] = {v1.x, v1.y};
    float o2[CPT] = {v2.x, v2.y};
    float o3[CPT] = {v3.x, v3.y};
    float o4[CPT] = {v4.x, v4.y};

    float aw = c_aw[a], ah = c_ah[a];
    float pxl[CPT], pxr[CPT], pyl[CPT], pyr[CPT], p6[CPT], maxv[CPT];
    #pragma unroll
    for (int c = 0; c < CPT; ++c) {
        float sx = sigmoidf(o0[c]), sy = sigmoidf(o1[c]);
        float px = sx + (float)(i0 + c);
        float py = sy + (float)j;
        float pw = __expf(o2[c]) * aw;
        float ph = __expf(o3[c]) * ah;
        pxl[c] = px - 0.5f*pw; pxr[c] = px + 0.5f*pw;
        pyl[c] = py - 0.5f*ph; pyr[c] = py + 0.5f*ph;
        p6[c]  = 0.6f*(pw*ph);
        maxv[c] = -1e30f;
    }

    const float* g = gt + b*(TT*8);        // block-uniform -> scalar loads
    #pragma unroll 5
    for (int t = 0; t < TT; ++t) {
        const float* r = g + t*8;
        float gxl = r[0], gxr = r[1], gyl = r[2], gyr = r[3], g06n = r[4];
        #pragma unroll
        for (int c = 0; c < CPT; ++c) {
            float cw = fminf(pxr[c], gxr) - fmaxf(pxl[c], gxl);
            float ch = fminf(pyr[c], gyr) - fmaxf(pyl[c], gyl);
            float carea = fmaxf(cw, 0.0f) * fmaxf(ch, 0.0f);
            maxv[c] = fmaxf(maxv[c], fmaf(1.6f, carea, g06n));
        }
    }

    float acc = 0.0f;
    #pragma unroll
    for (int c = 0; c < CPT; ++c) {
        float conf = sigmoidf(o4[c]);
        acc += (maxv[c] > p6[c]) ? 0.0f : 0.5f*conf*conf;
    }

    // wave64 + block reduction
    for (int off = 32; off > 0; off >>= 1) acc += __shfl_down(acc, off, 64);
    __shared__ float ssum[4];
    int lane = tid & 63, wid = tid >> 6;
    if (lane == 0) ssum[wid] = acc;
    __syncthreads();
    if (tid == 0) {
        float s = (ssum[0] + ssum[1]) + (ssum[2] + ssum[3]);
        atomicAdd(loss, s * (1.0f/NB));
    }
}

extern "C" void kernel_launch(void* const* d_in, const int* in_sizes, int n_in,
                              void* d_out, int out_size, void* d_ws, size_t ws_size,
                              hipStream_t stream) {
    const float* output = (const float*)d_in[0];
    const float* target = (const float*)d_in[1];
    float* gtbuf = (float*)d_ws;                 // NB*TT*8 floats = 25.6 KB
    float* out   = (float*)d_out;

    hipMemsetAsync(out, 0, (size_t)out_size*sizeof(float), stream);
    hipLaunchKernelGGL(prep_kernel, dim3(NB), dim3(64), 0, stream,
                       target, output, gtbuf, out);
    dim3 grid(APB/(256*CPT), NB);                // 90 x 16 = 1440 blocks
    hipLaunchKernelGGL(loss_kernel, grid, dim3(256), 0, stream,
                       output, gtbuf, out);
}

// Round 5
// 94.915 us; speedup vs baseline: 1.1090x; 1.1090x over previous
//
#include <hip/hip_runtime.h>
#include <math.h>

#define NB 16
#define NA 5
#define NH 96
#define NW 96
#define TT 50
#define HW (NH*NW)        // 9216
#define APB (NA*HW)       // 46080 cells per batch
#define CPT 4             // cells per thread in loss_kernel

__device__ __constant__ float c_aw[NA] = {1.3221f, 3.19275f, 5.05587f, 9.47112f, 11.2364f};
__device__ __constant__ float c_ah[NA] = {1.73145f, 4.00944f, 8.09892f, 4.84053f, 10.0071f};

__device__ __forceinline__ float sigmoidf(float x) { return 1.0f / (1.0f + __expf(-x)); }

// hot record  (8 floats / (b,t)): gxl,gxr,gyl,gyr,g06n(-0.6*garea or -1e30),0,0,0
// cold record (8 floats / (b,t)): garea,tx,ty,tw,th,tcls,lr,0   (assigned-cells only)
// map: per-cell winner GT index (or <0)
__global__ void prep_kernel(const float* __restrict__ target,
                            float* __restrict__ gth,
                            float* __restrict__ gtc,
                            int* __restrict__ map) {
    int b = blockIdx.x;
    int t = threadIdx.x;            // blockDim.x = 64 (one wave)
    __shared__ int s_cell[TT], s_valid[TT];

    float xraw = (t < TT) ? target[(b*TT + t)*6 + 1] : 1.0f;
    unsigned long long m = __ballot(xraw != 0.0f);

    int valid = 0, best = 0, cell = -1, gi = 0, gj = 0;
    float gx=0, gy=0, gw=1, gh=1, tcls=0, lr=0;
    if (t < TT) {
        valid = (((~m) & ((2ull << t) - 1ull)) == 0ull) ? 1 : 0;
        const float* tg = target + (b*TT + t)*6;
        tcls = tg[0];
        gx = tg[1]*NW; gy = tg[2]*NH; gw = tg[3]*NW; gh = tg[4]*NH;
        lr = tg[5];
        float bestiou = -1.0f;
        for (int a = 0; a < NA; ++a) {
            float inter = fminf(gw, c_aw[a]) * fminf(gh, c_ah[a]);
            float iou = inter / (gw*gh + c_aw[a]*c_ah[a] - inter);
            if (iou > bestiou) { bestiou = iou; best = a; }
        }
        gi = (int)gx; gj = (int)gy;
        cell = best*HW + gj*NW + gi;
        s_cell[t]  = valid ? cell : -1;
        s_valid[t] = valid;
    }
    __syncthreads();
    if (t < TT) {
        float* rh = gth + (b*TT + t)*8;
        if (valid) {
            rh[0] = gx - 0.5f*gw; rh[1] = gx + 0.5f*gw;
            rh[2] = gy - 0.5f*gh; rh[3] = gy + 0.5f*gh;
            rh[4] = -0.6f*gw*gh;
        } else {
            rh[0] = 0.0f; rh[1] = 0.0f; rh[2] = 0.0f; rh[3] = 0.0f;
            rh[4] = -1e30f;
        }
        rh[5] = 0.0f; rh[6] = 0.0f; rh[7] = 0.0f;
        float* rc = gtc + (b*TT + t)*8;
        rc[0] = gw*gh;
        rc[1] = gx - (float)gi;  rc[2] = gy - (float)gj;
        rc[3] = logf(gw / c_aw[best]); rc[4] = logf(gh / c_ah[best]);
        rc[5] = tcls; rc[6] = lr; rc[7] = 0.0f;
        // winner = last valid t mapping to this cell (scan scatter = last-write-wins)
        if (valid) {
            int winner = 1;
            for (int u = t + 1; u < TT; ++u)
                if (s_valid[u] && s_cell[u] == cell) { winner = 0; break; }
            if (winner) map[b*APB + cell] = t;
        }
    }
}

__global__ __launch_bounds__(256)
void loss_kernel(const float* __restrict__ outp,
                 const float* __restrict__ gth,
                 const float* __restrict__ gtc,
                 const int* __restrict__ map,
                 float* __restrict__ loss) {
    __shared__ float4 sgt4[TT*2];          // 50 records x 32B = 1600B
    float* sgt = (float*)sgt4;
    int b   = blockIdx.y;
    int tid = threadIdx.x;
    if (tid < TT*2) sgt4[tid] = ((const float4*)(gth + b*TT*8))[tid];
    __syncthreads();

    int q     = blockIdx.x*256 + tid;
    int cell0 = q*CPT;
    int a   = cell0 / HW;                  // 9216 = 9*1024: blocks never straddle a
    int rem = cell0 - a*HW;
    int j   = rem / NW;
    int i0  = rem - j*NW;                  // 4 | 96: never straddles a row

    const float* base = outp + (size_t)((b*NA + a)*8)*HW + rem;
    float4 v0 = *(const float4*)(base + 0*HW);
    float4 v1 = *(const float4*)(base + 1*HW);
    float4 v2 = *(const float4*)(base + 2*HW);
    float4 v3 = *(const float4*)(base + 3*HW);
    float4 v4 = *(const float4*)(base + 4*HW);
    float o0[CPT] = {v0.x, v0.y, v0.z, v0.w};
    float o1[CPT] = {v1.x, v1.y, v1.z, v1.w};
    float o2[CPT] = {v2.x, v2.y, v2.z, v2.w};
    float o3[CPT] = {v3.x, v3.y, v3.z, v3.w};
    float o4[CPT] = {v4.x, v4.y, v4.z, v4.w};

    float aw = c_aw[a], ah = c_ah[a];
    float pxl[CPT], pxr[CPT], pyl[CPT], pyr[CPT], parea[CPT], maxv[CPT];
    #pragma unroll
    for (int c = 0; c < CPT; ++c) {
        float sx = sigmoidf(o0[c]), sy = sigmoidf(o1[c]);
        float px = sx + (float)(i0 + c);
        float py = sy + (float)j;
        float pw = __expf(o2[c]) * aw;
        float ph = __expf(o3[c]) * ah;
        pxl[c] = px - 0.5f*pw; pxr[c] = px + 0.5f*pw;
        pyl[c] = py - 0.5f*ph; pyr[c] = py + 0.5f*ph;
        parea[c] = pw*ph;
        maxv[c] = -1e30f;
    }

    // GT loop: LDS broadcast reads, immediate offsets, no address VALU
    #pragma unroll 10
    for (int t = 0; t < TT; ++t) {
        float4 ra  = *(const float4*)(sgt + t*8);   // ds_read_b128
        float g06n = sgt[t*8 + 4];                  // ds_read_b32
        #pragma unroll
        for (int c = 0; c < CPT; ++c) {
            float cw = fminf(pxr[c], ra.y) - fmaxf(pxl[c], ra.x);
            float ch = fminf(pyr[c], ra.w) - fmaxf(pyl[c], ra.z);
            float carea = fmaxf(cw, 0.0f) * fmaxf(ch, 0.0f);
            maxv[c] = fmaxf(maxv[c], fmaf(1.6f, carea, g06n));
        }
    }

    int4 mp = *(const int4*)(map + b*APB + cell0); // coalesced winner lookup
    int mc[CPT] = {mp.x, mp.y, mp.z, mp.w};

    float acc = 0.0f;
    #pragma unroll
    for (int c = 0; c < CPT; ++c) {
        float conf = sigmoidf(o4[c]);
        int tw_idx = mc[c];
        if (tw_idx >= 0) {                         // rare (~800 / 737280 cells)
            const float* cr = gtc + (b*TT + tw_idx)*8;
            float garea = cr[0], tx = cr[1], ty = cr[2];
            float tw = cr[3], th = cr[4], tcls = cr[5], lr = cr[6];
            float gxl = sgt[tw_idx*8+0], gxr = sgt[tw_idx*8+1];
            float gyl = sgt[tw_idx*8+2], gyr = sgt[tw_idx*8+3];
            float cw = fminf(pxr[c], gxr) - fmaxf(pxl[c], gxl);
            float ch = fminf(pyr[c], gyr) - fmaxf(pyl[c], gyl);
            float carea = fmaxf(cw, 0.0f) * fmaxf(ch, 0.0f);
            float tconf = carea / (parea[c] + garea - carea);
            float dc = conf - tconf;
            float term = 2.5f*dc*dc;               // 0.5 * OBJECT_SCALE
            float sx = sigmoidf(o0[c]), sy = sigmoidf(o1[c]);
            float dx = sx - tx, dy = sy - ty, dw = o2[c] - tw, dh = o3[c] - th;
            term += 0.5f*(dx*dx + dy*dy + dw*dw + dh*dh);
            float o5 = base[5*HW + c], o6 = base[6*HW + c], o7 = base[7*HW + c];
            float mm  = fmaxf(o5, o6);
            float lse = mm + __logf(__expf(o5 - mm) + __expf(o6 - mm));
            term += lse - ((tcls != 0.0f) ? o6 : o5);   // 2-class CE
            float dl = sigmoidf(o7) - lr;
            term += 0.25f*dl*dl;                   // 0.5 * mse_half(conf_lr)
            acc += term;
        } else {
            acc += (maxv[c] > 0.6f*parea[c]) ? 0.0f : 0.5f*conf*conf;
        }
    }

    // wave64 + block reduction
    for (int off = 32; off > 0; off >>= 1) acc += __shfl_down(acc, off, 64);
    __shared__ float ssum[4];
    int lane = tid & 63, wid = tid >> 6;
    if (lane == 0) ssum[wid] = acc;
    __syncthreads();
    if (tid == 0) {
        float s = (ssum[0] + ssum[1]) + (ssum[2] + ssum[3]);
        atomicAdd(loss, s * (1.0f/NB));
    }
}

extern "C" void kernel_launch(void* const* d_in, const int* in_sizes, int n_in,
                              void* d_out, int out_size, void* d_ws, size_t ws_size,
                              hipStream_t stream) {
    const float* output = (const float*)d_in[0];
    const float* target = (const float*)d_in[1];
    float* gth = (float*)d_ws;                         // NB*TT*8 f = 25.6 KB
    float* gtc = gth + NB*TT*8;                        // NB*TT*8 f = 25.6 KB
    int*   map = (int*)((char*)d_ws + 65536);          // NB*APB ints = 2.95 MB
    float* out = (float*)d_out;

    hipMemsetAsync(out, 0, (size_t)out_size*sizeof(float), stream);
    hipMemsetAsync(map, 0xFF, (size_t)NB*APB*sizeof(int), stream);  // -1 everywhere
    hipLaunchKernelGGL(prep_kernel, dim3(NB), dim3(64), 0, stream,
                       target, gth, gtc, map);
    dim3 grid(APB/(256*CPT), NB);                      // 45 x 16 = 720 blocks
    hipLaunchKernelGGL(loss_kernel, grid, dim3(256), 0, stream,
                       output, gth, gtc, map, out);
}

// Round 6
// 86.280 us; speedup vs baseline: 1.2200x; 1.1001x over previous
//
#include <hip/hip_runtime.h>
#include <math.h>

#define NB 16
#define NA 5
#define NH 96
#define NW 96
#define TT 50
#define HW (NH*NW)        // 9216
#define APB (NA*HW)       // 46080 cells per batch
#define CPT 4             // cells per thread
#define CPB (256*CPT)     // 1024 cells per block

__device__ __constant__ float c_aw[NA] = {1.3221f, 3.19275f, 5.05587f, 9.47112f, 11.2364f};
__device__ __constant__ float c_ah[NA] = {1.73145f, 4.00944f, 8.09892f, 4.84053f, 10.0071f};

__device__ __forceinline__ float sigmoidf(float x) { return 1.0f / (1.0f + __expf(-x)); }

// Single fused kernel. Each block:
//  1. recomputes GT prep from raw target into LDS (one wave, redundant per block — cheap)
//  2. builds a per-block LDS winner map (cell -> GT index, -1 otherwise)
//  3. computes its 1024 cells' loss terms; one atomic per block.
__global__ __launch_bounds__(256)
void yolo_loss_fused(const float* __restrict__ outp,
                     const float* __restrict__ target,
                     float* __restrict__ loss) {
    __shared__ float s_hot[TT*8];    // gxl,gxr,gyl,gyr,g06n(-0.6*garea | -1e30),0,0,0
    __shared__ float s_cold[TT*8];   // garea,tx,ty,tw,th,tcls,lr,0
    __shared__ int   s_cell[TT];     // winner-candidate cell (-1 if invalid)
    __shared__ int   s_map[CPB];     // local cell -> winning GT index (-1)
    __shared__ float s_sum[4];

    int b   = blockIdx.y;
    int tid = threadIdx.x;
    int base_cell = blockIdx.x * CPB;

    #pragma unroll
    for (int k = 0; k < CPT; ++k) s_map[tid + k*256] = -1;

    if (tid < 64) {                    // wave 0 does GT prep
        int t = tid;
        float xraw = (t < TT) ? target[(b*TT + t)*6 + 1] : 1.0f;
        unsigned long long m = __ballot(xraw != 0.0f);
        if (t < TT) {
            int valid = (((~m) & ((2ull << t) - 1ull)) == 0ull) ? 1 : 0;
            const float* tg = target + (b*TT + t)*6;
            float tcls = tg[0];
            float gx = tg[1]*NW, gy = tg[2]*NH, gw = tg[3]*NW, gh = tg[4]*NH;
            float lr = tg[5];
            int best = 0; float bi = -1.0f;
            for (int a2 = 0; a2 < NA; ++a2) {
                float inter = fminf(gw, c_aw[a2]) * fminf(gh, c_ah[a2]);
                float iou = inter / (gw*gh + c_aw[a2]*c_ah[a2] - inter);
                if (iou > bi) { bi = iou; best = a2; }
            }
            int gi = (int)gx, gj = (int)gy;
            s_cell[t] = valid ? (best*HW + gj*NW + gi) : -1;
            float* rh = &s_hot[t*8];
            if (valid) {
                rh[0] = gx - 0.5f*gw; rh[1] = gx + 0.5f*gw;
                rh[2] = gy - 0.5f*gh; rh[3] = gy + 0.5f*gh;
                rh[4] = -0.6f*gw*gh;
            } else {
                rh[0] = 0.0f; rh[1] = 0.0f; rh[2] = 0.0f; rh[3] = 0.0f;
                rh[4] = -1e30f;
            }
            rh[5] = 0.0f; rh[6] = 0.0f; rh[7] = 0.0f;
            float* rc = &s_cold[t*8];
            rc[0] = gw*gh;
            rc[1] = gx - (float)gi;  rc[2] = gy - (float)gj;
            rc[3] = logf(gw / c_aw[best]); rc[4] = logf(gh / c_ah[best]);
            rc[5] = tcls; rc[6] = lr; rc[7] = 0.0f;
        }
    }
    __syncthreads();
    if (tid < TT) {
        int cell = s_cell[tid];
        if (cell >= 0) {
            // winner = last valid t mapping to this cell (scan scatter = last-write-wins)
            int winner = 1;
            for (int u = tid + 1; u < TT; ++u)
                if (s_cell[u] == cell) { winner = 0; break; }
            int local = cell - base_cell;
            if (winner && (unsigned)local < CPB) s_map[local] = tid;
        }
    }
    __syncthreads();

    int cell0 = base_cell + tid*CPT;
    int a   = cell0 / HW;                  // 9216 = 9*1024: blocks never straddle a
    int rem = cell0 - a*HW;
    int j   = rem / NW;
    int i0  = rem - j*NW;                  // 4 | 96: never straddles a row

    const float* base = outp + (size_t)((b*NA + a)*8)*HW + rem;
    float4 v0 = *(const float4*)(base + 0*HW);
    float4 v1 = *(const float4*)(base + 1*HW);
    float4 v2 = *(const float4*)(base + 2*HW);
    float4 v3 = *(const float4*)(base + 3*HW);
    float4 v4 = *(const float4*)(base + 4*HW);
    int4  mp  = *(const int4*)(&s_map[tid*CPT]);   // 16B/lane LDS, conflict-free
    float o0[CPT] = {v0.x, v0.y, v0.z, v0.w};
    float o1[CPT] = {v1.x, v1.y, v1.z, v1.w};
    float o2[CPT] = {v2.x, v2.y, v2.z, v2.w};
    float o3[CPT] = {v3.x, v3.y, v3.z, v3.w};
    float o4[CPT] = {v4.x, v4.y, v4.z, v4.w};
    int   mc[CPT] = {mp.x, mp.y, mp.z, mp.w};

    float aw = c_aw[a], ah = c_ah[a];
    float pxl[CPT], pxr[CPT], pyl[CPT], pyr[CPT], parea[CPT], maxv[CPT];
    #pragma unroll
    for (int c = 0; c < CPT; ++c) {
        float sx = sigmoidf(o0[c]), sy = sigmoidf(o1[c]);
        float px = sx + (float)(i0 + c);
        float py = sy + (float)j;
        float pw = __expf(o2[c]) * aw;
        float ph = __expf(o3[c]) * ah;
        pxl[c] = px - 0.5f*pw; pxr[c] = px + 0.5f*pw;
        pyl[c] = py - 0.5f*ph; pyr[c] = py + 0.5f*ph;
        parea[c] = pw*ph;
        maxv[c] = -1e30f;
    }

    // GT loop: LDS broadcast reads at immediate offsets, no address VALU
    #pragma unroll 10
    for (int t = 0; t < TT; ++t) {
        float4 ra  = *(const float4*)(&s_hot[t*8]);   // ds_read_b128
        float g06n = s_hot[t*8 + 4];                  // ds_read_b32
        #pragma unroll
        for (int c = 0; c < CPT; ++c) {
            float cw = fminf(pxr[c], ra.y) - fmaxf(pxl[c], ra.x);
            float ch = fminf(pyr[c], ra.w) - fmaxf(pyl[c], ra.z);
            float carea = fmaxf(cw, 0.0f) * fmaxf(ch, 0.0f);
            maxv[c] = fmaxf(maxv[c], fmaf(1.6f, carea, g06n));
        }
    }

    float acc = 0.0f;
    #pragma unroll
    for (int c = 0; c < CPT; ++c) {
        float conf = sigmoidf(o4[c]);
        int tw_idx = mc[c];
        if (tw_idx >= 0) {                         // rare (~800 / 737280 cells)
            const float* cr = &s_cold[tw_idx*8];
            float garea = cr[0], tx = cr[1], ty = cr[2];
            float tw = cr[3], th = cr[4], tcls = cr[5], lr = cr[6];
            const float* rh = &s_hot[tw_idx*8];
            float cw = fminf(pxr[c], rh[1]) - fmaxf(pxl[c], rh[0]);
            float ch = fminf(pyr[c], rh[3]) - fmaxf(pyl[c], rh[2]);
            float carea = fmaxf(cw, 0.0f) * fmaxf(ch, 0.0f);
            float tconf = carea / (parea[c] + garea - carea);
            float dc = conf - tconf;
            float term = 2.5f*dc*dc;               // 0.5 * OBJECT_SCALE
            float sx = sigmoidf(o0[c]), sy = sigmoidf(o1[c]);
            float dx = sx - tx, dy = sy - ty, dw = o2[c] - tw, dh = o3[c] - th;
            term += 0.5f*(dx*dx + dy*dy + dw*dw + dh*dh);
            float o5 = base[5*HW + c], o6 = base[6*HW + c], o7 = base[7*HW + c];
            float mm  = fmaxf(o5, o6);
            float lse = mm + __logf(__expf(o5 - mm) + __expf(o6 - mm));
            term += lse - ((tcls != 0.0f) ? o6 : o5);   // 2-class CE
            float dl = sigmoidf(o7) - lr;
            term += 0.25f*dl*dl;                   // 0.5 * mse_half(conf_lr)
            acc += term;
        } else {
            acc += (maxv[c] > 0.6f*parea[c]) ? 0.0f : 0.5f*conf*conf;
        }
    }

    // wave64 + block reduction, one atomic per block
    for (int off = 32; off > 0; off >>= 1) acc += __shfl_down(acc, off, 64);
    int lane = tid & 63, wid = tid >> 6;
    if (lane == 0) s_sum[wid] = acc;
    __syncthreads();
    if (tid == 0) {
        float s = (s_sum[0] + s_sum[1]) + (s_sum[2] + s_sum[3]);
        atomicAdd(loss, s * (1.0f/NB));
    }
}

extern "C" void kernel_launch(void* const* d_in, const int* in_sizes, int n_in,
                              void* d_out, int out_size, void* d_ws, size_t ws_size,
                              hipStream_t stream) {
    const float* output = (const float*)d_in[0];
    const float* target = (const float*)d_in[1];
    float* out = (float*)d_out;

    hipMemsetAsync(out, 0, (size_t)out_size*sizeof(float), stream);
    dim3 grid(APB/CPB, NB);                 // 45 x 16 = 720 blocks
    hipLaunchKernelGGL(yolo_loss_fused, grid, dim3(256), 0, stream,
                       output, target, out);
}